// Round 4
// baseline (4306.200 us; speedup 1.0000x reference)
//
#include <hip/hip_runtime.h>
#include <math.h>

// BinaryTreeLSTM — round 4: barrier-free K-loop.
//  * B (384x512 fp16, 384 KB) pre-packed in 8 gate-major 64-col slices of
//    48 KB; each block DMA-copies its slice to LDS once (global_load_lds
//    width=16), then the K-loop has NO __syncthreads at all.
//  * A fragments load straight from global to registers: for 16x16x32 MFMA a
//    lane needs 8 contiguous fp16 (16 B) of one row — a global_load_dwordx4.
//    emb is fp32 -> 2x float4 + cvt (chunks 0..3 only); h is stored fp16.
//  * Wave-tile 64 rows x 64 cols (4 m-frags x 4 gate-frags), acc = 64 VGPR;
//    4-wave blocks, 48 KB LDS -> 3 blocks/CU.
//  * Levels d=7..0 merged into ONE launch: 8 co-resident blocks + device-scope
//    atomic grid barrier (poison-tolerant init handshake via magic flag).

typedef _Float16 f16;
typedef f16 f16x8 __attribute__((ext_vector_type(8)));
typedef float f32x4 __attribute__((ext_vector_type(4)));

#define MAGIC 0xC0FFEEu

__device__ __forceinline__ float sigf(float x) { return 1.f / (1.f + __expf(-x)); }
__device__ __forceinline__ float tanh_fast(float x) { return 1.f - 2.f / (1.f + __expf(2.f * x)); }

__device__ __forceinline__ void load_lds_16(const void* g, void* l) {
    __builtin_amdgcn_global_load_lds(
        (const __attribute__((address_space(1))) unsigned int*)g,
        (__attribute__((address_space(3))) unsigned int*)l, 16, 0, 0);
}

// Bp layout: [by(8)][kci(12)][kq(4)][c(64)][k8(8)] fp16, c = g*16 + jl,
// orig row = g*256 + by*16 + jl, orig k = kci*32 + kq*8 + k8.
__global__ __launch_bounds__(256) void pack_weights(
    const float* __restrict__ W_ih, const float* __restrict__ W_hh,
    const float* __restrict__ b_ih, const float* __restrict__ b_hh,
    f16* __restrict__ Bp, float* __restrict__ biasP)
{
    int idx = blockIdx.x * 256 + threadIdx.x;
    if (idx < 196608) {
        int by = idx / 24576;
        int r = idx - by * 24576;
        int kci = r / 2048;
        int r2 = r & 2047;
        int kq = r2 >> 9;
        int r3 = r2 & 511;
        int c = r3 >> 3;
        int k8 = r3 & 7;
        int g = c >> 4, jl = c & 15;
        int rOrig = g * 256 + by * 16 + jl;
        int kk = kci * 32 + kq * 8 + k8;
        float w = (kk < 128) ? W_ih[(size_t)rOrig * 128 + kk]
                             : W_hh[(size_t)rOrig * 256 + (kk - 128)];
        Bp[idx] = (f16)w;
    }
    if (idx < 512) {
        int by = idx >> 6, c = idx & 63;
        int g = c >> 4, jl = c & 15;
        int rOrig = g * 256 + by * 16 + jl;
        biasP[idx] = b_ih[rOrig] + b_hh[rOrig];
    }
}

// One A fragment: 8 fp16 of row `row`, k = kci*32 + kq*8 .. +8.
__device__ __forceinline__ f16x8 loadA_frag(
    const float* __restrict__ emb, const f16* __restrict__ h_in,
    int n, int row, int kci, int kq)
{
    if (kci < 4) {
        const float* p = emb + (size_t)(n - 1 + row) * 128 + kci * 32 + kq * 8;
        float4 a = *(const float4*)p;
        float4 b = *(const float4*)(p + 4);
        f16x8 r;
        r[0] = (f16)a.x; r[1] = (f16)a.y; r[2] = (f16)a.z; r[3] = (f16)a.w;
        r[4] = (f16)b.x; r[5] = (f16)b.y; r[6] = (f16)b.z; r[7] = (f16)b.w;
        return r;
    }
    return *(const f16x8*)(h_in + (size_t)row * 256 + (kci - 4) * 32 + kq * 8);
}

// Big levels: n is a multiple of 256. grid = (8 by-slices, n/256).
__global__ __launch_bounds__(256) void level_big(
    const float* __restrict__ emb,
    const f16* __restrict__ Bp, const float* __restrict__ biasP,
    const f16* __restrict__ h_in,    // (n,256) fp16 child h
    const float* __restrict__ c_in,  // (n,256) fp32 child c
    f16* __restrict__ h_out,         // (n,128) fp16
    float* __restrict__ c_out,       // (n,128) fp32
    int n, int isTop)
{
    __shared__ __align__(16) f16 Bs[24576];   // 48 KB

    const int tid = threadIdx.x;
    const int lane = tid & 63;
    const int w = tid >> 6;
    const int by = blockIdx.x;
    const int row0 = blockIdx.y * 256 + w * 64;
    const int l15 = lane & 15;
    const int kq = lane >> 4;

    {   // B slice -> LDS, straight granule copy (12 x 16 B per thread)
        const char* gB = (const char*)(Bp + (size_t)by * 24576);
        char* lB = (char*)Bs;
        #pragma unroll
        for (int i = 0; i < 12; ++i)
            load_lds_16(gB + ((size_t)(i * 256 + tid)) * 16,
                        lB + ((size_t)(i * 256 + w * 64)) * 16);
    }

    f32x4 acc[4][4];
    #pragma unroll
    for (int a = 0; a < 4; ++a)
        #pragma unroll
        for (int b = 0; b < 4; ++b) acc[a][b] = (f32x4)0.f;

    const int nch = isTop ? 4 : 12;

    f16x8 af[2][4];
    #pragma unroll
    for (int mi = 0; mi < 4; ++mi)
        af[0][mi] = loadA_frag(emb, h_in, n, row0 + mi * 16 + l15, 0, kq);

    __syncthreads();   // B resident; only barrier in the kernel

    for (int kci = 0; kci < nch; ++kci) {
        int cur = kci & 1;
        if (kci + 1 < nch) {
            #pragma unroll
            for (int mi = 0; mi < 4; ++mi)
                af[cur ^ 1][mi] = loadA_frag(emb, h_in, n, row0 + mi * 16 + l15, kci + 1, kq);
        }
        f16x8 bf[4];
        #pragma unroll
        for (int g = 0; g < 4; ++g)
            bf[g] = *(const f16x8*)&Bs[((kci * 4 + kq) * 64 + g * 16 + l15) * 8];
        #pragma unroll
        for (int mi = 0; mi < 4; ++mi)
            #pragma unroll
            for (int g = 0; g < 4; ++g)
                acc[mi][g] = __builtin_amdgcn_mfma_f32_16x16x32_f16(
                    af[cur][mi], bf[g], acc[mi][g], 0, 0, 0);
    }

    // Epilogue: gates register-local (gate == n-frag index)
    const int j = by * 16 + l15;
    const float bi = biasP[by * 64 + 0 + l15];
    const float bfv = biasP[by * 64 + 16 + l15];
    const float bg = biasP[by * 64 + 32 + l15];
    const float bo = biasP[by * 64 + 48 + l15];
    #pragma unroll
    for (int mi = 0; mi < 4; ++mi) {
        #pragma unroll
        for (int r = 0; r < 4; ++r) {
            int row = row0 + mi * 16 + kq * 4 + r;
            float gi = acc[mi][0][r] + bi;
            float gf = acc[mi][1][r] + bfv;
            float gg = acc[mi][2][r] + bg;
            float go = acc[mi][3][r] + bo;
            float cl = isTop ? 0.f : c_in[(size_t)row * 256 + j];
            float cn = sigf(gf) * cl + sigf(gi) * tanh_fast(gg);
            float hn = sigf(go) * tanh_fast(cn);
            h_out[(size_t)row * 128 + j] = (f16)hn;
            c_out[(size_t)row * 128 + j] = cn;
        }
    }
}

__device__ __forceinline__ void grid_bar(unsigned* cnt, unsigned target) {
    __syncthreads();
    if (threadIdx.x == 0) {
        __threadfence();
        __hip_atomic_fetch_add(cnt, 1u, __ATOMIC_ACQ_REL, __HIP_MEMORY_SCOPE_AGENT);
        while (__hip_atomic_load(cnt, __ATOMIC_ACQUIRE, __HIP_MEMORY_SCOPE_AGENT) < target)
            __builtin_amdgcn_s_sleep(8);
        __threadfence();
    }
    __syncthreads();
}

// Levels d=7..0 in one launch. grid = (8,1); 8 blocks co-resident.
__global__ __launch_bounds__(256) void levels_small(
    const float* __restrict__ emb,
    const f16* __restrict__ Bp, const float* __restrict__ biasP,
    f16* hA, float* cA,        // input to d=7 (output of d=8)
    f16* hB, float* cB,        // scratch pair
    float* root_out, unsigned* sync)
{
    __shared__ __align__(16) f16 Bs[24576];

    const int tid = threadIdx.x;
    const int lane = tid & 63;
    const int w = tid >> 6;
    const int by = blockIdx.x;
    const int row0 = w * 64;
    const int l15 = lane & 15;
    const int kq = lane >> 4;

    {   // B slice -> LDS once
        const char* gB = (const char*)(Bp + (size_t)by * 24576);
        char* lB = (char*)Bs;
        #pragma unroll
        for (int i = 0; i < 12; ++i)
            load_lds_16(gB + ((size_t)(i * 256 + tid)) * 16,
                        lB + ((size_t)(i * 256 + w * 64)) * 16);
    }

    // Poison-tolerant init handshake (ws is re-poisoned 0xAA each launch)
    if (blockIdx.x == 0 && threadIdx.x == 0) {
        __hip_atomic_store(&sync[0], 0u, __ATOMIC_RELAXED, __HIP_MEMORY_SCOPE_AGENT);
        __hip_atomic_store(&sync[1], MAGIC, __ATOMIC_RELEASE, __HIP_MEMORY_SCOPE_AGENT);
    }
    if (threadIdx.x == 0) {
        while (__hip_atomic_load(&sync[1], __ATOMIC_ACQUIRE, __HIP_MEMORY_SCOPE_AGENT) != MAGIC)
            __builtin_amdgcn_s_sleep(8);
    }
    __syncthreads();   // B resident + counter initialized

    const int j = by * 16 + l15;
    const float bi = biasP[by * 64 + 0 + l15];
    const float bfv = biasP[by * 64 + 16 + l15];
    const float bg = biasP[by * 64 + 32 + l15];
    const float bo = biasP[by * 64 + 48 + l15];

    f16* hptr[2] = { hA, hB };
    float* cptr[2] = { cA, cB };
    int p = 0;
    unsigned phase = 0;

    for (int d = 7; d >= 0; --d) {
        const int n = 1 << d;
        const f16* h_in = hptr[p];
        const float* c_in = cptr[p];
        f16* h_out = hptr[p ^ 1];
        float* c_out = cptr[p ^ 1];

        f32x4 acc[4][4];
        #pragma unroll
        for (int a = 0; a < 4; ++a)
            #pragma unroll
            for (int b = 0; b < 4; ++b) acc[a][b] = (f32x4)0.f;

        f16x8 af[2][4];
        #pragma unroll
        for (int mi = 0; mi < 4; ++mi) {
            int row = row0 + mi * 16 + l15; if (row >= n) row = n - 1;
            af[0][mi] = loadA_frag(emb, h_in, n, row, 0, kq);
        }
        for (int kci = 0; kci < 12; ++kci) {
            int cur = kci & 1;
            if (kci + 1 < 12) {
                #pragma unroll
                for (int mi = 0; mi < 4; ++mi) {
                    int row = row0 + mi * 16 + l15; if (row >= n) row = n - 1;
                    af[cur ^ 1][mi] = loadA_frag(emb, h_in, n, row, kci + 1, kq);
                }
            }
            f16x8 bf[4];
            #pragma unroll
            for (int g = 0; g < 4; ++g)
                bf[g] = *(const f16x8*)&Bs[((kci * 4 + kq) * 64 + g * 16 + l15) * 8];
            #pragma unroll
            for (int mi = 0; mi < 4; ++mi)
                #pragma unroll
                for (int g = 0; g < 4; ++g)
                    acc[mi][g] = __builtin_amdgcn_mfma_f32_16x16x32_f16(
                        af[cur][mi], bf[g], acc[mi][g], 0, 0, 0);
        }

        #pragma unroll
        for (int mi = 0; mi < 4; ++mi) {
            #pragma unroll
            for (int r = 0; r < 4; ++r) {
                int row = row0 + mi * 16 + kq * 4 + r;
                if (row < n) {
                    float gi = acc[mi][0][r] + bi;
                    float gf = acc[mi][1][r] + bfv;
                    float gg = acc[mi][2][r] + bg;
                    float go = acc[mi][3][r] + bo;
                    float cl = c_in[(size_t)row * 256 + j];
                    float cn = sigf(gf) * cl + sigf(gi) * tanh_fast(gg);
                    float hn = sigf(go) * tanh_fast(cn);
                    if (d == 0) {
                        root_out[j] = hn;
                        root_out[128 + j] = cn;
                    } else {
                        h_out[(size_t)row * 128 + j] = (f16)hn;
                        c_out[(size_t)row * 128 + j] = cn;
                    }
                }
            }
        }

        if (d > 0) {
            ++phase;
            grid_bar(&sync[0], 8u * phase);
        }
        p ^= 1;
    }
}

extern "C" void kernel_launch(void* const* d_in, const int* in_sizes, int n_in,
                              void* d_out, int out_size, void* d_ws, size_t ws_size,
                              hipStream_t stream) {
    const float* emb  = (const float*)d_in[0];
    const float* W_ih = (const float*)d_in[1];
    const float* W_hh = (const float*)d_in[2];
    const float* b_ih = (const float*)d_in[3];
    const float* b_hh = (const float*)d_in[4];

    char* wsb = (char*)d_ws;
    f16*   Bp    = (f16*)wsb;                      // 393216 B
    float* biasP = (float*)(wsb + 393216);         // 2048 B
    unsigned* syncp = (unsigned*)(wsb + 397312);   // 2 words
    char*  bufs  = wsb + 1048576;
    const size_t HBUF = (size_t)131072 * 128 * sizeof(f16);   // 32 MiB
    const size_t CBUF = (size_t)131072 * 128 * sizeof(float); // 64 MiB
    f16* hbuf[2]   = { (f16*)bufs, (f16*)(bufs + HBUF) };
    float* cbuf[2] = { (float*)(bufs + 2 * HBUF), (float*)(bufs + 2 * HBUF + CBUF) };
    if (ws_size < 1048576 + 2 * HBUF + 2 * CBUF) return;

    pack_weights<<<768, 256, 0, stream>>>(W_ih, W_hh, b_ih, b_hh, Bp, biasP);

    int wr = 0;
    for (int d = 17; d >= 8; --d) {
        int n = 1 << d;
        int isTop = (d == 17);
        const f16* hin   = isTop ? nullptr : hbuf[wr ^ 1];
        const float* cin = isTop ? nullptr : cbuf[wr ^ 1];
        dim3 grid(8, n >> 8);
        level_big<<<grid, 256, 0, stream>>>(emb, Bp, biasP, hin, cin,
                                            hbuf[wr], cbuf[wr], n, isTop);
        wr ^= 1;
    }
    // d=8 wrote hbuf[wr^1]/cbuf[wr^1]; that's the input to d=7.
    levels_small<<<dim3(8), 256, 0, stream>>>(emb, Bp, biasP,
        hbuf[wr ^ 1], cbuf[wr ^ 1], hbuf[wr], cbuf[wr],
        (float*)d_out, syncp);
}

// Round 5
// 586.298 us; speedup vs baseline: 7.3447x; 7.3447x over previous
//
#include <hip/hip_runtime.h>
#include <math.h>

// BinaryTreeLSTM — round 5: round-4 structure with the spill + XCD bugs fixed.
//  * B (384x512 fp16) pre-packed in 8 gate-major 64-col slices of 48 KB;
//    each block DMAs its slice to LDS once (global_load_lds w=16); K-loop has
//    no barriers.
//  * A fragments global->register, double-buffered. Chunk loop is a template
//    constant (NCH) and fully unrolled so af[kci&1] constant-folds to
//    registers (round 4's runtime trip count demoted it to scratch: VGPR=84,
//    MfmaUtil 0.7%).
//  * Block swizzle: bid -> xcd=bid&7, s=bid>>3, by=s&7, rb=xcd+8*(s>>3).
//    The 8 by-siblings sharing an A-tile get the same (id mod 8) => same XCD,
//    adjacent slots => co-resident => A re-reads hit that XCD's L2.
//  * Levels d=7..0 merged in one cooperative-style launch (8 blocks,
//    device-scope atomic barrier, poison-tolerant init handshake).

typedef _Float16 f16;
typedef f16 f16x8 __attribute__((ext_vector_type(8)));
typedef float f32x4 __attribute__((ext_vector_type(4)));

#define MAGIC 0xC0FFEEu

__device__ __forceinline__ float sigf(float x) { return 1.f / (1.f + __expf(-x)); }
__device__ __forceinline__ float tanh_fast(float x) { return 1.f - 2.f / (1.f + __expf(2.f * x)); }

__device__ __forceinline__ void load_lds_16(const void* g, void* l) {
    __builtin_amdgcn_global_load_lds(
        (const __attribute__((address_space(1))) unsigned int*)g,
        (__attribute__((address_space(3))) unsigned int*)l, 16, 0, 0);
}

// Bp layout: [by(8)][kci(12)][kq(4)][c(64)][k8(8)] fp16, c = g*16 + jl,
// orig row = g*256 + by*16 + jl, orig k = kci*32 + kq*8 + k8.
__global__ __launch_bounds__(256) void pack_weights(
    const float* __restrict__ W_ih, const float* __restrict__ W_hh,
    const float* __restrict__ b_ih, const float* __restrict__ b_hh,
    f16* __restrict__ Bp, float* __restrict__ biasP)
{
    int idx = blockIdx.x * 256 + threadIdx.x;
    if (idx < 196608) {
        int by = idx / 24576;
        int r = idx - by * 24576;
        int kci = r / 2048;
        int r2 = r & 2047;
        int kq = r2 >> 9;
        int r3 = r2 & 511;
        int c = r3 >> 3;
        int k8 = r3 & 7;
        int g = c >> 4, jl = c & 15;
        int rOrig = g * 256 + by * 16 + jl;
        int kk = kci * 32 + kq * 8 + k8;
        float w = (kk < 128) ? W_ih[(size_t)rOrig * 128 + kk]
                             : W_hh[(size_t)rOrig * 256 + (kk - 128)];
        Bp[idx] = (f16)w;
    }
    if (idx < 512) {
        int by = idx >> 6, c = idx & 63;
        int g = c >> 4, jl = c & 15;
        int rOrig = g * 256 + by * 16 + jl;
        biasP[idx] = b_ih[rOrig] + b_hh[rOrig];
    }
}

// One A fragment: 8 fp16 of row `row`, k = kci*32 + kq*8 .. +8.
__device__ __forceinline__ f16x8 loadA_frag(
    const float* __restrict__ emb, const f16* __restrict__ h_in,
    int n, int row, int kci, int kq)
{
    if (kci < 4) {
        const float* p = emb + (size_t)(n - 1 + row) * 128 + kci * 32 + kq * 8;
        float4 a = *(const float4*)p;
        float4 b = *(const float4*)(p + 4);
        f16x8 r;
        r[0] = (f16)a.x; r[1] = (f16)a.y; r[2] = (f16)a.z; r[3] = (f16)a.w;
        r[4] = (f16)b.x; r[5] = (f16)b.y; r[6] = (f16)b.z; r[7] = (f16)b.w;
        return r;
    }
    return *(const f16x8*)(h_in + (size_t)row * 256 + (kci - 4) * 32 + kq * 8);
}

// Big levels: n multiple of 256. grid = (8, n/256). NCH compile-time.
template <int NCH, int SWIZ>
__global__ __launch_bounds__(256, 3) void level_big(
    const float* __restrict__ emb,
    const f16* __restrict__ Bp, const float* __restrict__ biasP,
    const f16* __restrict__ h_in,    // (n,256) fp16 child h
    const float* __restrict__ c_in,  // (n,256) fp32 child c
    f16* __restrict__ h_out,         // (n,128) fp16
    float* __restrict__ c_out,       // (n,128) fp32
    int n)
{
    __shared__ __align__(16) f16 Bs[24576];   // 48 KB

    const int tid = threadIdx.x;
    const int lane = tid & 63;
    const int w = tid >> 6;
    const int l15 = lane & 15;
    const int kq = lane >> 4;

    int by, rb;
    if (SWIZ) {
        int bid = blockIdx.y * 8 + blockIdx.x;   // dispatch-linear id
        int xcd = bid & 7;
        int s = bid >> 3;
        by = s & 7;
        rb = xcd + 8 * (s >> 3);
    } else {
        by = blockIdx.x;
        rb = blockIdx.y;
    }
    const int row0 = rb * 256 + w * 64;

    {   // B slice -> LDS, straight granule copy
        const char* gB = (const char*)(Bp + (size_t)by * 24576);
        char* lB = (char*)Bs;
        #pragma unroll
        for (int i = 0; i < 12; ++i)
            load_lds_16(gB + ((size_t)(i * 256 + tid)) * 16,
                        lB + ((size_t)(i * 256 + w * 64)) * 16);
    }

    f32x4 acc[4][4];
    #pragma unroll
    for (int a = 0; a < 4; ++a)
        #pragma unroll
        for (int b = 0; b < 4; ++b) acc[a][b] = (f32x4)0.f;

    f16x8 af[2][4];
    #pragma unroll
    for (int mi = 0; mi < 4; ++mi)
        af[0][mi] = loadA_frag(emb, h_in, n, row0 + mi * 16 + l15, 0, kq);

    __syncthreads();   // B resident; only barrier in the kernel

    #pragma unroll
    for (int kci = 0; kci < NCH; ++kci) {
        const int cur = kci & 1;
        if (kci + 1 < NCH) {
            #pragma unroll
            for (int mi = 0; mi < 4; ++mi)
                af[cur ^ 1][mi] =
                    loadA_frag(emb, h_in, n, row0 + mi * 16 + l15, kci + 1, kq);
        }
        f16x8 bf[4];
        #pragma unroll
        for (int g = 0; g < 4; ++g)
            bf[g] = *(const f16x8*)&Bs[((kci * 4 + kq) * 64 + g * 16 + l15) * 8];
        #pragma unroll
        for (int mi = 0; mi < 4; ++mi)
            #pragma unroll
            for (int g = 0; g < 4; ++g)
                acc[mi][g] = __builtin_amdgcn_mfma_f32_16x16x32_f16(
                    af[cur][mi], bf[g], acc[mi][g], 0, 0, 0);
    }

    // Epilogue: gates register-local (gate == n-frag index)
    const int j = by * 16 + l15;
    const float bi = biasP[by * 64 + 0 + l15];
    const float bfv = biasP[by * 64 + 16 + l15];
    const float bg = biasP[by * 64 + 32 + l15];
    const float bo = biasP[by * 64 + 48 + l15];
    #pragma unroll
    for (int mi = 0; mi < 4; ++mi) {
        #pragma unroll
        for (int r = 0; r < 4; ++r) {
            int row = row0 + mi * 16 + kq * 4 + r;
            float gi = acc[mi][0][r] + bi;
            float gf = acc[mi][1][r] + bfv;
            float gg = acc[mi][2][r] + bg;
            float go = acc[mi][3][r] + bo;
            float cl = (NCH == 4) ? 0.f : c_in[(size_t)row * 256 + j];
            float cn = sigf(gf) * cl + sigf(gi) * tanh_fast(gg);
            float hn = sigf(go) * tanh_fast(cn);
            h_out[(size_t)row * 128 + j] = (f16)hn;
            c_out[(size_t)row * 128 + j] = cn;
        }
    }
}

__device__ __forceinline__ void grid_bar(unsigned* cnt, unsigned target) {
    __syncthreads();
    if (threadIdx.x == 0) {
        __threadfence();
        __hip_atomic_fetch_add(cnt, 1u, __ATOMIC_ACQ_REL, __HIP_MEMORY_SCOPE_AGENT);
        while (__hip_atomic_load(cnt, __ATOMIC_ACQUIRE, __HIP_MEMORY_SCOPE_AGENT) < target)
            __builtin_amdgcn_s_sleep(8);
        __threadfence();
    }
    __syncthreads();
}

// Levels d=7..0 in one launch. grid = (8,1); 8 blocks co-resident.
__global__ __launch_bounds__(256) void levels_small(
    const float* __restrict__ emb,
    const f16* __restrict__ Bp, const float* __restrict__ biasP,
    f16* hA, float* cA,        // input to d=7 (output of d=8)
    f16* hB, float* cB,        // scratch pair
    float* root_out, unsigned* sync)
{
    __shared__ __align__(16) f16 Bs[24576];

    const int tid = threadIdx.x;
    const int lane = tid & 63;
    const int w = tid >> 6;
    const int by = blockIdx.x;
    const int row0 = w * 64;
    const int l15 = lane & 15;
    const int kq = lane >> 4;

    {   // B slice -> LDS once
        const char* gB = (const char*)(Bp + (size_t)by * 24576);
        char* lB = (char*)Bs;
        #pragma unroll
        for (int i = 0; i < 12; ++i)
            load_lds_16(gB + ((size_t)(i * 256 + tid)) * 16,
                        lB + ((size_t)(i * 256 + w * 64)) * 16);
    }

    // Poison-tolerant init handshake (ws is re-poisoned 0xAA each launch)
    if (blockIdx.x == 0 && threadIdx.x == 0) {
        __hip_atomic_store(&sync[0], 0u, __ATOMIC_RELAXED, __HIP_MEMORY_SCOPE_AGENT);
        __hip_atomic_store(&sync[1], MAGIC, __ATOMIC_RELEASE, __HIP_MEMORY_SCOPE_AGENT);
    }
    if (threadIdx.x == 0) {
        while (__hip_atomic_load(&sync[1], __ATOMIC_ACQUIRE, __HIP_MEMORY_SCOPE_AGENT) != MAGIC)
            __builtin_amdgcn_s_sleep(8);
    }
    __syncthreads();   // B resident + counter initialized

    const int j = by * 16 + l15;
    const float bi = biasP[by * 64 + 0 + l15];
    const float bfv = biasP[by * 64 + 16 + l15];
    const float bg = biasP[by * 64 + 32 + l15];
    const float bo = biasP[by * 64 + 48 + l15];

    f16* hptr[2] = { hA, hB };
    float* cptr[2] = { cA, cB };
    int p = 0;
    unsigned phase = 0;

    for (int d = 7; d >= 0; --d) {
        const int n = 1 << d;
        const f16* h_in = hptr[p];
        const float* c_in = cptr[p];
        f16* h_out = hptr[p ^ 1];
        float* c_out = cptr[p ^ 1];

        f32x4 acc[4][4];
        #pragma unroll
        for (int a = 0; a < 4; ++a)
            #pragma unroll
            for (int b = 0; b < 4; ++b) acc[a][b] = (f32x4)0.f;

        f16x8 af[2][4];
        #pragma unroll
        for (int mi = 0; mi < 4; ++mi) {
            int row = row0 + mi * 16 + l15; if (row >= n) row = n - 1;
            af[0][mi] = loadA_frag(emb, h_in, n, row, 0, kq);
        }
        #pragma unroll
        for (int kci = 0; kci < 12; ++kci) {
            const int cur = kci & 1;
            if (kci + 1 < 12) {
                #pragma unroll
                for (int mi = 0; mi < 4; ++mi) {
                    int row = row0 + mi * 16 + l15; if (row >= n) row = n - 1;
                    af[cur ^ 1][mi] = loadA_frag(emb, h_in, n, row, kci + 1, kq);
                }
            }
            f16x8 bf[4];
            #pragma unroll
            for (int g = 0; g < 4; ++g)
                bf[g] = *(const f16x8*)&Bs[((kci * 4 + kq) * 64 + g * 16 + l15) * 8];
            #pragma unroll
            for (int mi = 0; mi < 4; ++mi)
                #pragma unroll
                for (int g = 0; g < 4; ++g)
                    acc[mi][g] = __builtin_amdgcn_mfma_f32_16x16x32_f16(
                        af[cur][mi], bf[g], acc[mi][g], 0, 0, 0);
        }

        #pragma unroll
        for (int mi = 0; mi < 4; ++mi) {
            #pragma unroll
            for (int r = 0; r < 4; ++r) {
                int row = row0 + mi * 16 + kq * 4 + r;
                if (row < n) {
                    float gi = acc[mi][0][r] + bi;
                    float gf = acc[mi][1][r] + bfv;
                    float gg = acc[mi][2][r] + bg;
                    float go = acc[mi][3][r] + bo;
                    float cl = c_in[(size_t)row * 256 + j];
                    float cn = sigf(gf) * cl + sigf(gi) * tanh_fast(gg);
                    float hn = sigf(go) * tanh_fast(cn);
                    if (d == 0) {
                        root_out[j] = hn;
                        root_out[128 + j] = cn;
                    } else {
                        h_out[(size_t)row * 128 + j] = (f16)hn;
                        c_out[(size_t)row * 128 + j] = cn;
                    }
                }
            }
        }

        if (d > 0) {
            ++phase;
            grid_bar(&sync[0], 8u * phase);
        }
        p ^= 1;
    }
}

extern "C" void kernel_launch(void* const* d_in, const int* in_sizes, int n_in,
                              void* d_out, int out_size, void* d_ws, size_t ws_size,
                              hipStream_t stream) {
    const float* emb  = (const float*)d_in[0];
    const float* W_ih = (const float*)d_in[1];
    const float* W_hh = (const float*)d_in[2];
    const float* b_ih = (const float*)d_in[3];
    const float* b_hh = (const float*)d_in[4];

    char* wsb = (char*)d_ws;
    f16*   Bp    = (f16*)wsb;                      // 393216 B
    float* biasP = (float*)(wsb + 393216);         // 2048 B
    unsigned* syncp = (unsigned*)(wsb + 397312);   // 2 words
    char*  bufs  = wsb + 1048576;
    const size_t HBUF = (size_t)131072 * 128 * sizeof(f16);   // 32 MiB
    const size_t CBUF = (size_t)131072 * 128 * sizeof(float); // 64 MiB
    f16* hbuf[2]   = { (f16*)bufs, (f16*)(bufs + HBUF) };
    float* cbuf[2] = { (float*)(bufs + 2 * HBUF), (float*)(bufs + 2 * HBUF + CBUF) };
    if (ws_size < 1048576 + 2 * HBUF + 2 * CBUF) return;

    pack_weights<<<768, 256, 0, stream>>>(W_ih, W_hh, b_ih, b_hh, Bp, biasP);

    int wr = 0;
    for (int d = 17; d >= 8; --d) {
        int n = 1 << d;
        dim3 grid(8, n >> 8);
        int R = n >> 8;
        const f16* hin   = (d == 17) ? nullptr : hbuf[wr ^ 1];
        const float* cin = (d == 17) ? nullptr : cbuf[wr ^ 1];
        if (d == 17) {
            level_big<4, 1><<<grid, 256, 0, stream>>>(emb, Bp, biasP, hin, cin,
                                                      hbuf[wr], cbuf[wr], n);
        } else if (R % 8 == 0) {
            level_big<12, 1><<<grid, 256, 0, stream>>>(emb, Bp, biasP, hin, cin,
                                                       hbuf[wr], cbuf[wr], n);
        } else {
            level_big<12, 0><<<grid, 256, 0, stream>>>(emb, Bp, biasP, hin, cin,
                                                       hbuf[wr], cbuf[wr], n);
        }
        wr ^= 1;
    }
    // d=8 wrote hbuf[wr^1]/cbuf[wr^1]; that's the input to d=7.
    levels_small<<<dim3(8), 256, 0, stream>>>(emb, Bp, biasP,
        hbuf[wr ^ 1], cbuf[wr ^ 1], hbuf[wr], cbuf[wr],
        (float*)d_out, syncp);
}

// Round 6
// 483.393 us; speedup vs baseline: 8.9083x; 1.2129x over previous
//
#include <hip/hip_runtime.h>
#include <math.h>

// BinaryTreeLSTM — round 6: fast epilogue, fp16 emb pre-pass, depth-3
// prefetch ring, packed (even-only) c.
//  * B (384x512 fp16) pre-packed in 8 gate-major 64-col slices of 48 KB;
//    one LDS DMA per block, no barriers in the K-loop.
//  * A fragments global->register (single dwordx4 each now that emb is fp16),
//    ring-buffered 3 chunks deep, fully unrolled (template NCH).
//  * sigmoid/tanh via v_exp + v_rcp intrinsics (no IEEE-div expansion;
//    round 5 d=17 was VALU-bound at 47% on v_div_* + v_cvt).
//  * c is only ever read for LEFT children -> write even rows only, packed
//    (n/2,128); halves c traffic.
//  * XCD swizzle so the 8 by-siblings sharing an A tile land on one XCD.

typedef _Float16 f16;
typedef f16 f16x8 __attribute__((ext_vector_type(8)));
typedef float f32x4 __attribute__((ext_vector_type(4)));

#define MAGIC 0xC0FFEEu
#define LOG2E 1.44269504f

__device__ __forceinline__ float sigf(float x) {
    return __builtin_amdgcn_rcpf(1.f + __builtin_amdgcn_exp2f(-x * LOG2E));
}
__device__ __forceinline__ float tanh_fast(float x) {
    return 1.f - 2.f * __builtin_amdgcn_rcpf(1.f + __builtin_amdgcn_exp2f(2.f * x * LOG2E));
}

__device__ __forceinline__ void load_lds_16(const void* g, void* l) {
    __builtin_amdgcn_global_load_lds(
        (const __attribute__((address_space(1))) unsigned int*)g,
        (__attribute__((address_space(3))) unsigned int*)l, 16, 0, 0);
}

// Bp layout: [by(8)][kci(12)][kq(4)][c(64)][k8(8)] fp16, c = g*16 + jl,
// orig row = g*256 + by*16 + jl, orig k = kci*32 + kq*8 + k8.
__global__ __launch_bounds__(256) void pack_weights(
    const float* __restrict__ W_ih, const float* __restrict__ W_hh,
    const float* __restrict__ b_ih, const float* __restrict__ b_hh,
    f16* __restrict__ Bp, float* __restrict__ biasP)
{
    int idx = blockIdx.x * 256 + threadIdx.x;
    if (idx < 196608) {
        int by = idx / 24576;
        int r = idx - by * 24576;
        int kci = r / 2048;
        int r2 = r & 2047;
        int kq = r2 >> 9;
        int r3 = r2 & 511;
        int c = r3 >> 3;
        int k8 = r3 & 7;
        int g = c >> 4, jl = c & 15;
        int rOrig = g * 256 + by * 16 + jl;
        int kk = kci * 32 + kq * 8 + k8;
        float w = (kk < 128) ? W_ih[(size_t)rOrig * 128 + kk]
                             : W_hh[(size_t)rOrig * 256 + (kk - 128)];
        Bp[idx] = (f16)w;
    }
    if (idx < 512) {
        int by = idx >> 6, c = idx & 63;
        int g = c >> 4, jl = c & 15;
        int rOrig = g * 256 + by * 16 + jl;
        biasP[idx] = b_ih[rOrig] + b_hh[rOrig];
    }
}

// emb fp32 -> fp16, 8 elems/thread. 262143*128 = 33554304 elems.
__global__ __launch_bounds__(256) void emb_cvt(
    const float* __restrict__ emb, f16* __restrict__ embH)
{
    int i = blockIdx.x * 256 + threadIdx.x;
    if (i < 4194288) {
        const float4 a = *(const float4*)(emb + (size_t)i * 8);
        const float4 b = *(const float4*)(emb + (size_t)i * 8 + 4);
        f16x8 r;
        r[0] = (f16)a.x; r[1] = (f16)a.y; r[2] = (f16)a.z; r[3] = (f16)a.w;
        r[4] = (f16)b.x; r[5] = (f16)b.y; r[6] = (f16)b.z; r[7] = (f16)b.w;
        *(f16x8*)(embH + (size_t)i * 8) = r;
    }
}

// One A fragment: 8 fp16 of row `row`, k = kci*32 + kq*8 .. +8.
__device__ __forceinline__ f16x8 loadA(
    const f16* __restrict__ embH, const f16* __restrict__ h_in,
    int n, int row, int kci, int kq)
{
    const f16* p = (kci < 4)
        ? embH + (size_t)(n - 1 + row) * 128 + kci * 32 + kq * 8
        : h_in + (size_t)row * 256 + (kci - 4) * 32 + kq * 8;
    return *(const f16x8*)p;
}

// Big levels: n multiple of 256. grid = (8, n/256). NCH compile-time.
template <int NCH, int SWIZ>
__global__ __launch_bounds__(256, 3) void level_big(
    const f16* __restrict__ embH,
    const f16* __restrict__ Bp, const float* __restrict__ biasP,
    const f16* __restrict__ h_in,    // (n,256) fp16 child h
    const float* __restrict__ c_in,  // (n,128) fp32 packed left-child c
    f16* __restrict__ h_out,         // (n,128) fp16
    float* __restrict__ c_out,       // (n/2,128) fp32 packed (even rows only)
    int n)
{
    __shared__ __align__(16) f16 Bs[24576];   // 48 KB

    const int tid = threadIdx.x;
    const int lane = tid & 63;
    const int w = tid >> 6;
    const int l15 = lane & 15;
    const int kq = lane >> 4;

    int by, rb;
    if (SWIZ) {
        int bid = blockIdx.y * 8 + blockIdx.x;   // dispatch-linear id
        int xcd = bid & 7;
        int s = bid >> 3;
        by = s & 7;
        rb = xcd + 8 * (s >> 3);
    } else {
        by = blockIdx.x;
        rb = blockIdx.y;
    }
    const int row0 = rb * 256 + w * 64;

    {   // B slice -> LDS, straight granule copy
        const char* gB = (const char*)(Bp + (size_t)by * 24576);
        char* lB = (char*)Bs;
        #pragma unroll
        for (int i = 0; i < 12; ++i)
            load_lds_16(gB + ((size_t)(i * 256 + tid)) * 16,
                        lB + ((size_t)(i * 256 + w * 64)) * 16);
    }

    f32x4 acc[4][4];
    #pragma unroll
    for (int a = 0; a < 4; ++a)
        #pragma unroll
        for (int b = 0; b < 4; ++b) acc[a][b] = (f32x4)0.f;

    // depth-3 prefetch ring
    f16x8 af[3][4];
    #pragma unroll
    for (int pk = 0; pk < 3; ++pk) {
        if (pk < NCH) {
            #pragma unroll
            for (int mi = 0; mi < 4; ++mi)
                af[pk][mi] = loadA(embH, h_in, n, row0 + mi * 16 + l15, pk, kq);
        }
    }

    __syncthreads();   // B resident; only barrier in the kernel

    #pragma unroll
    for (int kci = 0; kci < NCH; ++kci) {
        const int sl = kci % 3;
        f16x8 bf[4];
        #pragma unroll
        for (int g = 0; g < 4; ++g)
            bf[g] = *(const f16x8*)&Bs[((kci * 4 + kq) * 64 + g * 16 + l15) * 8];
        f16x8 a0 = af[sl][0], a1 = af[sl][1], a2 = af[sl][2], a3 = af[sl][3];
        if (kci + 3 < NCH) {
            #pragma unroll
            for (int mi = 0; mi < 4; ++mi)
                af[sl][mi] = loadA(embH, h_in, n, row0 + mi * 16 + l15, kci + 3, kq);
        }
        #pragma unroll
        for (int g = 0; g < 4; ++g) {
            acc[0][g] = __builtin_amdgcn_mfma_f32_16x16x32_f16(a0, bf[g], acc[0][g], 0, 0, 0);
            acc[1][g] = __builtin_amdgcn_mfma_f32_16x16x32_f16(a1, bf[g], acc[1][g], 0, 0, 0);
            acc[2][g] = __builtin_amdgcn_mfma_f32_16x16x32_f16(a2, bf[g], acc[2][g], 0, 0, 0);
            acc[3][g] = __builtin_amdgcn_mfma_f32_16x16x32_f16(a3, bf[g], acc[3][g], 0, 0, 0);
        }
    }

    // Epilogue: gates register-local (gate == n-frag index)
    const int j = by * 16 + l15;
    const float bi = biasP[by * 64 + 0 + l15];
    const float bfv = biasP[by * 64 + 16 + l15];
    const float bg = biasP[by * 64 + 32 + l15];
    const float bo = biasP[by * 64 + 48 + l15];
    #pragma unroll
    for (int mi = 0; mi < 4; ++mi) {
        #pragma unroll
        for (int r = 0; r < 4; ++r) {
            int row = row0 + mi * 16 + kq * 4 + r;
            float gi = acc[mi][0][r] + bi;
            float gf = acc[mi][1][r] + bfv;
            float gg = acc[mi][2][r] + bg;
            float go = acc[mi][3][r] + bo;
            float cl = (NCH == 4) ? 0.f : c_in[(size_t)row * 128 + j];
            float cn = sigf(gf) * cl + sigf(gi) * tanh_fast(gg);
            float hn = sigf(go) * tanh_fast(cn);
            h_out[(size_t)row * 128 + j] = (f16)hn;
            if (!(row & 1))
                c_out[(size_t)(row >> 1) * 128 + j] = cn;
        }
    }
}

__device__ __forceinline__ void grid_bar(unsigned* cnt, unsigned target) {
    __syncthreads();
    if (threadIdx.x == 0) {
        __threadfence();
        __hip_atomic_fetch_add(cnt, 1u, __ATOMIC_ACQ_REL, __HIP_MEMORY_SCOPE_AGENT);
        while (__hip_atomic_load(cnt, __ATOMIC_ACQUIRE, __HIP_MEMORY_SCOPE_AGENT) < target)
            __builtin_amdgcn_s_sleep(8);
        __threadfence();
    }
    __syncthreads();
}

// Levels d=7..0 in one launch. grid = (8,1); 8 blocks co-resident.
__global__ __launch_bounds__(256) void levels_small(
    const f16* __restrict__ embH,
    const f16* __restrict__ Bp, const float* __restrict__ biasP,
    f16* hA, float* cA,        // input to d=7 (h full, c packed from d=8)
    f16* hB, float* cB,        // scratch pair
    float* root_out, unsigned* sync)
{
    __shared__ __align__(16) f16 Bs[24576];

    const int tid = threadIdx.x;
    const int lane = tid & 63;
    const int w = tid >> 6;
    const int by = blockIdx.x;
    const int row0 = w * 64;
    const int l15 = lane & 15;
    const int kq = lane >> 4;

    {   // B slice -> LDS once
        const char* gB = (const char*)(Bp + (size_t)by * 24576);
        char* lB = (char*)Bs;
        #pragma unroll
        for (int i = 0; i < 12; ++i)
            load_lds_16(gB + ((size_t)(i * 256 + tid)) * 16,
                        lB + ((size_t)(i * 256 + w * 64)) * 16);
    }

    // Poison-tolerant init handshake (ws is re-poisoned 0xAA each launch)
    if (blockIdx.x == 0 && threadIdx.x == 0) {
        __hip_atomic_store(&sync[0], 0u, __ATOMIC_RELAXED, __HIP_MEMORY_SCOPE_AGENT);
        __hip_atomic_store(&sync[1], MAGIC, __ATOMIC_RELEASE, __HIP_MEMORY_SCOPE_AGENT);
    }
    if (threadIdx.x == 0) {
        while (__hip_atomic_load(&sync[1], __ATOMIC_ACQUIRE, __HIP_MEMORY_SCOPE_AGENT) != MAGIC)
            __builtin_amdgcn_s_sleep(8);
    }
    __syncthreads();   // B resident + counter initialized

    const int j = by * 16 + l15;
    const float bi = biasP[by * 64 + 0 + l15];
    const float bfv = biasP[by * 64 + 16 + l15];
    const float bg = biasP[by * 64 + 32 + l15];
    const float bo = biasP[by * 64 + 48 + l15];

    f16* hptr[2] = { hA, hB };
    float* cptr[2] = { cA, cB };
    int p = 0;
    unsigned phase = 0;

    for (int d = 7; d >= 0; --d) {
        const int n = 1 << d;
        const f16* h_in = hptr[p];
        const float* c_in = cptr[p];
        f16* h_out = hptr[p ^ 1];
        float* c_out = cptr[p ^ 1];

        f32x4 acc[4][4];
        #pragma unroll
        for (int a = 0; a < 4; ++a)
            #pragma unroll
            for (int b = 0; b < 4; ++b) acc[a][b] = (f32x4)0.f;

        f16x8 af[3][4];
        #pragma unroll
        for (int pk = 0; pk < 3; ++pk) {
            #pragma unroll
            for (int mi = 0; mi < 4; ++mi) {
                int row = row0 + mi * 16 + l15; if (row >= n) row = n - 1;
                af[pk][mi] = loadA(embH, h_in, n, row, pk, kq);
            }
        }
        #pragma unroll
        for (int kci = 0; kci < 12; ++kci) {
            const int sl = kci % 3;
            f16x8 bf[4];
            #pragma unroll
            for (int g = 0; g < 4; ++g)
                bf[g] = *(const f16x8*)&Bs[((kci * 4 + kq) * 64 + g * 16 + l15) * 8];
            f16x8 a0 = af[sl][0], a1 = af[sl][1], a2 = af[sl][2], a3 = af[sl][3];
            if (kci + 3 < 12) {
                #pragma unroll
                for (int mi = 0; mi < 4; ++mi) {
                    int row = row0 + mi * 16 + l15; if (row >= n) row = n - 1;
                    af[sl][mi] = loadA(embH, h_in, n, row, kci + 3, kq);
                }
            }
            #pragma unroll
            for (int g = 0; g < 4; ++g) {
                acc[0][g] = __builtin_amdgcn_mfma_f32_16x16x32_f16(a0, bf[g], acc[0][g], 0, 0, 0);
                acc[1][g] = __builtin_amdgcn_mfma_f32_16x16x32_f16(a1, bf[g], acc[1][g], 0, 0, 0);
                acc[2][g] = __builtin_amdgcn_mfma_f32_16x16x32_f16(a2, bf[g], acc[2][g], 0, 0, 0);
                acc[3][g] = __builtin_amdgcn_mfma_f32_16x16x32_f16(a3, bf[g], acc[3][g], 0, 0, 0);
            }
        }

        #pragma unroll
        for (int mi = 0; mi < 4; ++mi) {
            #pragma unroll
            for (int r = 0; r < 4; ++r) {
                int row = row0 + mi * 16 + kq * 4 + r;
                if (row < n) {
                    float gi = acc[mi][0][r] + bi;
                    float gf = acc[mi][1][r] + bfv;
                    float gg = acc[mi][2][r] + bg;
                    float go = acc[mi][3][r] + bo;
                    float cl = c_in[(size_t)row * 128 + j];
                    float cn = sigf(gf) * cl + sigf(gi) * tanh_fast(gg);
                    float hn = sigf(go) * tanh_fast(cn);
                    if (d == 0) {
                        root_out[j] = hn;
                        root_out[128 + j] = cn;
                    } else {
                        h_out[(size_t)row * 128 + j] = (f16)hn;
                        if (!(row & 1))
                            c_out[(size_t)(row >> 1) * 128 + j] = cn;
                    }
                }
            }
        }

        if (d > 0) {
            ++phase;
            grid_bar(&sync[0], 8u * phase);
        }
        p ^= 1;
    }
}

extern "C" void kernel_launch(void* const* d_in, const int* in_sizes, int n_in,
                              void* d_out, int out_size, void* d_ws, size_t ws_size,
                              hipStream_t stream) {
    const float* emb  = (const float*)d_in[0];
    const float* W_ih = (const float*)d_in[1];
    const float* W_hh = (const float*)d_in[2];
    const float* b_ih = (const float*)d_in[3];
    const float* b_hh = (const float*)d_in[4];

    char* wsb = (char*)d_ws;
    f16*   Bp    = (f16*)wsb;                      // 393216 B
    float* biasP = (float*)(wsb + 393216);         // 2048 B
    unsigned* syncp = (unsigned*)(wsb + 397312);   // 8 B
    f16*   embH  = (f16*)(wsb + 1048576);          // 67108608 B used
    char*  bufs  = wsb + 1048576 + 67108864;
    const size_t HBUF = (size_t)131072 * 128 * sizeof(f16);   // 32 MiB
    const size_t CBUF = (size_t)65536 * 128 * sizeof(float);  // 32 MiB (packed)
    f16* hbuf[2]   = { (f16*)bufs, (f16*)(bufs + HBUF) };
    float* cbuf[2] = { (float*)(bufs + 2 * HBUF), (float*)(bufs + 2 * HBUF + CBUF) };
    if (ws_size < 1048576 + 67108864 + 2 * HBUF + 2 * CBUF) return;

    pack_weights<<<768, 256, 0, stream>>>(W_ih, W_hh, b_ih, b_hh, Bp, biasP);
    emb_cvt<<<16384, 256, 0, stream>>>(emb, embH);

    int wr = 0;
    for (int d = 17; d >= 8; --d) {
        int n = 1 << d;
        int R = n >> 8;
        dim3 grid(8, R);
        const f16* hin   = (d == 17) ? nullptr : hbuf[wr ^ 1];
        const float* cin = (d == 17) ? nullptr : cbuf[wr ^ 1];
        if (d == 17) {
            level_big<4, 1><<<grid, 256, 0, stream>>>(embH, Bp, biasP, hin, cin,
                                                      hbuf[wr], cbuf[wr], n);
        } else if (R % 8 == 0) {
            level_big<12, 1><<<grid, 256, 0, stream>>>(embH, Bp, biasP, hin, cin,
                                                       hbuf[wr], cbuf[wr], n);
        } else {
            level_big<12, 0><<<grid, 256, 0, stream>>>(embH, Bp, biasP, hin, cin,
                                                       hbuf[wr], cbuf[wr], n);
        }
        wr ^= 1;
    }
    // d=8 wrote hbuf[wr^1]/cbuf[wr^1]; that's the input to d=7.
    levels_small<<<dim3(8), 256, 0, stream>>>(embH, Bp, biasP,
        hbuf[wr ^ 1], cbuf[wr ^ 1], hbuf[wr], cbuf[wr],
        (float*)d_out, syncp);
}